// Round 1
// baseline (457.037 us; speedup 1.0000x reference)
//
#include <hip/hip_runtime.h>
#include <math.h>

namespace {
constexpr int kB   = 32;
constexpr int kC   = 64;
constexpr int kT   = 8192;
constexpr int kOUT = 129;
constexpr int kKK  = 1024;   // K*K
constexpr int kNFC = 8;      // f-chunks
constexpr int kFCH = 128;    // f per chunk
constexpr float kTwoPi = 6.28318530717958647692f;
}

// ---------------------------------------------------------------------------
// Kernel 1: partial a[b,o,c] over one f-chunk of 128 frequencies.
// grid = B*kNFC blocks, 512 threads. LDS holds cos/sin[f'][c] (66 KB).
// Each wave (og = tid/64) owns o in {og, og+8, ...}; lane = channel c.
// ---------------------------------------------------------------------------
__global__ __launch_bounds__(512) void sa_phase_dot(
    const float* __restrict__ positions,
    const float* __restrict__ z_real,
    const float* __restrict__ z_imag,
    float* __restrict__ part)
{
  __shared__ float s_cos[kFCH][kC];
  __shared__ float s_sin[kFCH][kC];
  __shared__ float s_px[kC];
  __shared__ float s_py[kC];

  const int b   = blockIdx.x >> 3;
  const int fc  = blockIdx.x & 7;
  const int f0  = fc * kFCH;
  const int tid = threadIdx.x;

  if (tid < kC) {
    float2 p = reinterpret_cast<const float2*>(positions)[b * kC + tid];
    s_px[tid] = p.x;
    s_py[tid] = p.y;
  }
  __syncthreads();

  // stage sincos: 128*64 entries, 16 per thread. layout [f'][c] -> lane-consecutive reads.
  for (int e = tid; e < kFCH * kC; e += 512) {
    const int fp = e >> 6;
    const int c  = e & 63;
    const int f  = f0 + fp;
    const float kf = (float)((f & 31) + 1);   // coef_k = (f % K) + 1
    const float lf = (float)((f >> 5) + 1);   // coef_l = (f / K) + 1
    const float ph = kTwoPi * (s_px[c] * kf + s_py[c] * lf);
    float sv, cv;
    sincosf(ph, &sv, &cv);
    s_cos[fp][c] = cv;
    s_sin[fp][c] = sv;
  }
  __syncthreads();

  const int og = tid >> 6;   // 0..7 (wave id)
  const int c  = tid & 63;   // channel = lane

  float acc[17];
#pragma unroll
  for (int j = 0; j < 17; ++j) acc[j] = 0.f;

  for (int fq = 0; fq < kFCH / 4; ++fq) {
    const float cv0 = s_cos[4*fq+0][c], cv1 = s_cos[4*fq+1][c];
    const float cv2 = s_cos[4*fq+2][c], cv3 = s_cos[4*fq+3][c];
    const float sv0 = s_sin[4*fq+0][c], sv1 = s_sin[4*fq+1][c];
    const float sv2 = s_sin[4*fq+2][c], sv3 = s_sin[4*fq+3][c];
#pragma unroll
    for (int j = 0; j < 17; ++j) {
      const int o = og + 8*j;
      if (o < kOUT) {
        const float4 zr = *reinterpret_cast<const float4*>(z_real + o*kKK + f0 + 4*fq);
        const float4 zi = *reinterpret_cast<const float4*>(z_imag + o*kKK + f0 + 4*fq);
        float a = acc[j];
        a = fmaf(zr.x, cv0, a); a = fmaf(zi.x, sv0, a);
        a = fmaf(zr.y, cv1, a); a = fmaf(zi.y, sv1, a);
        a = fmaf(zr.z, cv2, a); a = fmaf(zi.z, sv2, a);
        a = fmaf(zr.w, cv3, a); a = fmaf(zi.w, sv3, a);
        acc[j] = a;
      }
    }
  }

#pragma unroll
  for (int j = 0; j < 17; ++j) {
    const int o = og + 8*j;
    if (o < kOUT)
      part[((fc*kB + b)*kOUT + o)*kC + c] = acc[j];
  }
}

// ---------------------------------------------------------------------------
// Kernel 2: reduce partials, apply channel-drop mask, softmax over c (64 lanes).
// grid = B*OUT blocks of 64 threads (one wave each).
// ---------------------------------------------------------------------------
__global__ __launch_bounds__(64) void sa_softmax(
    const float* __restrict__ part,
    const float* __restrict__ positions,
    const int*   __restrict__ drop_idx,
    float* __restrict__ attn)
{
  const int bo = blockIdx.x;           // b*OUT + o
  const int b  = bo / kOUT;
  const int o  = bo - b * kOUT;
  const int c  = threadIdx.x;

  float a = 0.f;
#pragma unroll
  for (int fc = 0; fc < kNFC; ++fc)
    a += part[((fc*kB + b)*kOUT + o)*kC + c];

  const float2 p  = reinterpret_cast<const float2*>(positions)[b*kC + c];
  const int    di = drop_idx[b];
  const float2 pd = reinterpret_cast<const float2*>(positions)[b*kC + di];
  const float dx = p.x - pd.x;
  const float dy = p.y - pd.y;
  // forbid fma contraction so the >= 0.1 comparison matches the reference order
  const float d2 = __fadd_rn(__fmul_rn(dx, dx), __fmul_rn(dy, dy));
  if (d2 < 0.1f) a = -1e9f;

  float m = a;
#pragma unroll
  for (int off = 32; off; off >>= 1) m = fmaxf(m, __shfl_xor(m, off));
  const float e = expf(a - m);
  float s = e;
#pragma unroll
  for (int off = 32; off; off >>= 1) s += __shfl_xor(s, off);

  attn[bo * kC + c] = e / s;
}

// ---------------------------------------------------------------------------
// Kernel 3: out[b,o,t] = sum_c attn[b,o,c] * X[b,c,t].
// grid = B*16 blocks, 256 threads; each thread owns 2 consecutive t (float2).
// X column (64 channels) held in 128 VGPRs, fully static indexing.
// ---------------------------------------------------------------------------
__global__ __launch_bounds__(256) void sa_apply(
    const float* __restrict__ X,
    const float* __restrict__ attn,
    float* __restrict__ out)
{
  const int b  = blockIdx.x >> 4;      // 32 batches
  const int tc = blockIdx.x & 15;      // 16 t-chunks of 512
  const int tq = tc * 256 + threadIdx.x;   // float2 index within T/2 = 4096

  const float2* __restrict__ X2 = reinterpret_cast<const float2*>(X);
  float2* __restrict__ out2 = reinterpret_cast<float2*>(out);

  float2 x[kC];
#pragma unroll
  for (int c = 0; c < kC; ++c)
    x[c] = X2[(b*kC + c)*(kT/2) + tq];

  const float4* __restrict__ A4 =
      reinterpret_cast<const float4*>(attn + b*kOUT*kC);

  for (int o = 0; o < kOUT; ++o) {
    float a0x = 0.f, a0y = 0.f, a1x = 0.f, a1y = 0.f;
#pragma unroll
    for (int c4 = 0; c4 < 8; ++c4) {
      const float4 w = A4[o*16 + c4];
      a0x = fmaf(w.x, x[4*c4+0].x, a0x); a0y = fmaf(w.x, x[4*c4+0].y, a0y);
      a0x = fmaf(w.y, x[4*c4+1].x, a0x); a0y = fmaf(w.y, x[4*c4+1].y, a0y);
      a0x = fmaf(w.z, x[4*c4+2].x, a0x); a0y = fmaf(w.z, x[4*c4+2].y, a0y);
      a0x = fmaf(w.w, x[4*c4+3].x, a0x); a0y = fmaf(w.w, x[4*c4+3].y, a0y);
    }
#pragma unroll
    for (int c4 = 8; c4 < 16; ++c4) {
      const float4 w = A4[o*16 + c4];
      a1x = fmaf(w.x, x[4*c4+0].x, a1x); a1y = fmaf(w.x, x[4*c4+0].y, a1y);
      a1x = fmaf(w.y, x[4*c4+1].x, a1x); a1y = fmaf(w.y, x[4*c4+1].y, a1y);
      a1x = fmaf(w.z, x[4*c4+2].x, a1x); a1y = fmaf(w.z, x[4*c4+2].y, a1y);
      a1x = fmaf(w.w, x[4*c4+3].x, a1x); a1y = fmaf(w.w, x[4*c4+3].y, a1y);
    }
    float2 r;
    r.x = a0x + a1x;
    r.y = a0y + a1y;
    out2[(b*kOUT + o)*(kT/2) + tq] = r;
  }
}

// ---------------------------------------------------------------------------
extern "C" void kernel_launch(void* const* d_in, const int* in_sizes, int n_in,
                              void* d_out, int out_size, void* d_ws, size_t ws_size,
                              hipStream_t stream) {
  (void)in_sizes; (void)n_in; (void)out_size; (void)ws_size;
  const float* X         = (const float*)d_in[0];
  const float* positions = (const float*)d_in[1];
  const int*   drop_idx  = (const int*)d_in[2];
  const float* z_real    = (const float*)d_in[3];
  const float* z_imag    = (const float*)d_in[4];
  float* out = (float*)d_out;

  float* part = (float*)d_ws;                       // [kNFC][B][OUT][C] f32, 8.45 MB
  float* attn = part + (size_t)kNFC*kB*kOUT*kC;     // [B][OUT][C] f32, 1.06 MB

  sa_phase_dot<<<kB*kNFC, 512, 0, stream>>>(positions, z_real, z_imag, part);
  sa_softmax<<<kB*kOUT, 64, 0, stream>>>(part, positions, drop_idx, attn);
  sa_apply<<<kB*16, 256, 0, stream>>>(X, attn, out);
}

// Round 2
// 345.140 us; speedup vs baseline: 1.3242x; 1.3242x over previous
//
#include <hip/hip_runtime.h>
#include <math.h>

namespace {
constexpr int kB   = 32;
constexpr int kC   = 64;
constexpr int kT   = 8192;
constexpr int kOUT = 129;
constexpr int kKK  = 1024;   // K*K
constexpr int kNFC = 8;      // f-chunks
constexpr int kFCH = 128;    // f per chunk
constexpr float kTwoPi = 6.28318530717958647692f;
}

// ---------------------------------------------------------------------------
// Kernel 1: partial a[b,o,c] over one f-chunk of 128 frequencies.
// grid = B*kNFC = 256 blocks, 512 threads. LDS: sincos[f'][c] (65 KB, computed
// once) + z double-pass buffer (66 KB). Two o-passes (o<64, o>=64) share the
// z buffer. Compute loop touches ONLY LDS: per-lane sincos reads (conflict-
// free) + wave-uniform z reads (broadcast). No global loads in the hot loop.
// Wave og owns o = og + 8*j.
// ---------------------------------------------------------------------------
__global__ __launch_bounds__(512) void sa_phase_dot(
    const float* __restrict__ positions,
    const float* __restrict__ z_real,
    const float* __restrict__ z_imag,
    float* __restrict__ part)
{
  __shared__ float  s_cos[kFCH][kC];       // 32.75 KB
  __shared__ float  s_sin[kFCH][kC];       // 32.75 KB
  __shared__ float4 s_zr4[65 * kFCH / 4];  // 33.3 KB (65 o-rows x 128 f)
  __shared__ float4 s_zi4[65 * kFCH / 4];  // 33.3 KB
  __shared__ float  s_px[kC];
  __shared__ float  s_py[kC];

  const int b   = blockIdx.x >> 3;
  const int fc  = blockIdx.x & 7;
  const int f0  = fc * kFCH;
  const int tid = threadIdx.x;

  if (tid < kC) {
    float2 p = reinterpret_cast<const float2*>(positions)[b * kC + tid];
    s_px[tid] = p.x;
    s_py[tid] = p.y;
  }

  // stage z pass A (o = 0..63): 64 rows * 32 float4 per array
  {
    const float4* zr = reinterpret_cast<const float4*>(z_real);
    const float4* zi = reinterpret_cast<const float4*>(z_imag);
    for (int i = tid; i < 64 * 32; i += 512) {
      const int r = i >> 5, q = i & 31;           // row, quad-within-row
      const int g = r * (kKK / 4) + (f0 / 4) + q; // global float4 index
      s_zr4[i] = zr[g];
      s_zi4[i] = zi[g];
    }
  }
  __syncthreads();

  // sincos table: 128*64 entries, 16 per thread
  for (int e = tid; e < kFCH * kC; e += 512) {
    const int fp = e >> 6;
    const int c  = e & 63;
    const int f  = f0 + fp;
    const float kf = (float)((f & 31) + 1);   // coef_k = (f % K) + 1
    const float lf = (float)((f >> 5) + 1);   // coef_l = (f / K) + 1
    const float ph = kTwoPi * (s_px[c] * kf + s_py[c] * lf);
    float sv, cv;
    sincosf(ph, &sv, &cv);
    s_cos[fp][c] = cv;
    s_sin[fp][c] = sv;
  }
  __syncthreads();

  const int og = tid >> 6;   // wave id 0..7
  const int c  = tid & 63;   // channel = lane

  // ---- pass A: o = og + 8*j, j = 0..7 (o in [0,64)) ----
  {
    float acc[8];
#pragma unroll
    for (int j = 0; j < 8; ++j) acc[j] = 0.f;

    for (int fq = 0; fq < kFCH / 4; ++fq) {
      const float cv0 = s_cos[4*fq+0][c], cv1 = s_cos[4*fq+1][c];
      const float cv2 = s_cos[4*fq+2][c], cv3 = s_cos[4*fq+3][c];
      const float sv0 = s_sin[4*fq+0][c], sv1 = s_sin[4*fq+1][c];
      const float sv2 = s_sin[4*fq+2][c], sv3 = s_sin[4*fq+3][c];
#pragma unroll
      for (int j = 0; j < 8; ++j) {
        const int row = og + 8*j;
        const float4 zr = s_zr4[row * 32 + fq];
        const float4 zi = s_zi4[row * 32 + fq];
        float a = acc[j];
        a = fmaf(zr.x, cv0, a); a = fmaf(zi.x, sv0, a);
        a = fmaf(zr.y, cv1, a); a = fmaf(zi.y, sv1, a);
        a = fmaf(zr.z, cv2, a); a = fmaf(zi.z, sv2, a);
        a = fmaf(zr.w, cv3, a); a = fmaf(zi.w, sv3, a);
        acc[j] = a;
      }
    }
#pragma unroll
    for (int j = 0; j < 8; ++j) {
      const int o = og + 8*j;
      part[((fc*kB + b)*kOUT + o)*kC + c] = acc[j];
    }
  }

  __syncthreads();  // everyone done reading pass-A z

  // stage z pass B (o = 64..128): 65 rows
  {
    const float4* zr = reinterpret_cast<const float4*>(z_real);
    const float4* zi = reinterpret_cast<const float4*>(z_imag);
    for (int i = tid; i < 65 * 32; i += 512) {
      const int r = i >> 5, q = i & 31;
      const int g = (64 + r) * (kKK / 4) + (f0 / 4) + q;
      s_zr4[i] = zr[g];
      s_zi4[i] = zi[g];
    }
  }
  __syncthreads();

  // ---- pass B: o = 64 + og + 8*j, j = 0..8 (guard o < 129) ----
  {
    float acc[9];
#pragma unroll
    for (int j = 0; j < 9; ++j) acc[j] = 0.f;

    for (int fq = 0; fq < kFCH / 4; ++fq) {
      const float cv0 = s_cos[4*fq+0][c], cv1 = s_cos[4*fq+1][c];
      const float cv2 = s_cos[4*fq+2][c], cv3 = s_cos[4*fq+3][c];
      const float sv0 = s_sin[4*fq+0][c], sv1 = s_sin[4*fq+1][c];
      const float sv2 = s_sin[4*fq+2][c], sv3 = s_sin[4*fq+3][c];
#pragma unroll
      for (int j = 0; j < 9; ++j) {
        const int row = og + 8*j;
        if (row < 65) {
          const float4 zr = s_zr4[row * 32 + fq];
          const float4 zi = s_zi4[row * 32 + fq];
          float a = acc[j];
          a = fmaf(zr.x, cv0, a); a = fmaf(zi.x, sv0, a);
          a = fmaf(zr.y, cv1, a); a = fmaf(zi.y, sv1, a);
          a = fmaf(zr.z, cv2, a); a = fmaf(zi.z, sv2, a);
          a = fmaf(zr.w, cv3, a); a = fmaf(zi.w, sv3, a);
          acc[j] = a;
        }
      }
    }
#pragma unroll
    for (int j = 0; j < 9; ++j) {
      const int o = 64 + og + 8*j;
      if (o < kOUT)
        part[((fc*kB + b)*kOUT + o)*kC + c] = acc[j];
    }
  }
}

// ---------------------------------------------------------------------------
// Kernel 2: reduce partials, apply channel-drop mask, softmax over c (64 lanes).
// grid = B*OUT blocks of 64 threads (one wave each).
// ---------------------------------------------------------------------------
__global__ __launch_bounds__(64) void sa_softmax(
    const float* __restrict__ part,
    const float* __restrict__ positions,
    const int*   __restrict__ drop_idx,
    float* __restrict__ attn)
{
  const int bo = blockIdx.x;           // b*OUT + o
  const int b  = bo / kOUT;
  const int o  = bo - b * kOUT;
  const int c  = threadIdx.x;

  float a = 0.f;
#pragma unroll
  for (int fc = 0; fc < kNFC; ++fc)
    a += part[((fc*kB + b)*kOUT + o)*kC + c];

  const float2 p  = reinterpret_cast<const float2*>(positions)[b*kC + c];
  const int    di = drop_idx[b];
  const float2 pd = reinterpret_cast<const float2*>(positions)[b*kC + di];
  const float dx = p.x - pd.x;
  const float dy = p.y - pd.y;
  // forbid fma contraction so the >= 0.1 comparison matches the reference order
  const float d2 = __fadd_rn(__fmul_rn(dx, dx), __fmul_rn(dy, dy));
  if (d2 < 0.1f) a = -1e9f;

  float m = a;
#pragma unroll
  for (int off = 32; off; off >>= 1) m = fmaxf(m, __shfl_xor(m, off));
  const float e = expf(a - m);
  float s = e;
#pragma unroll
  for (int off = 32; off; off >>= 1) s += __shfl_xor(s, off);

  attn[bo * kC + c] = e / s;
}

// ---------------------------------------------------------------------------
// Kernel 3: out[b,o,t] = sum_c attn[b,o,c] * X[b,c,t].
// grid = B*16 blocks, 256 threads; each thread owns 2 consecutive t (float2).
// X column (64 channels) in 128 VGPRs; attn[b] staged in LDS (33 KB), the
// o-loop reads it as wave-uniform broadcast ds_read_b128 (no global latency).
// ---------------------------------------------------------------------------
__global__ __launch_bounds__(256) void sa_apply(
    const float* __restrict__ X,
    const float* __restrict__ attn,
    float* __restrict__ out)
{
  __shared__ float s_attn[kOUT * kC];  // 33 KB

  const int b  = blockIdx.x >> 4;      // 32 batches
  const int tc = blockIdx.x & 15;      // 16 t-chunks of 512
  const int tq = tc * 256 + threadIdx.x;   // float2 index within T/2 = 4096

  // stage attn[b] into LDS (coalesced float4)
  {
    const float4* Ag = reinterpret_cast<const float4*>(attn + b * kOUT * kC);
    float4* sA = reinterpret_cast<float4*>(s_attn);
    for (int i = threadIdx.x; i < kOUT * kC / 4; i += 256) sA[i] = Ag[i];
  }

  const float2* __restrict__ X2 = reinterpret_cast<const float2*>(X);
  float2* __restrict__ out2 = reinterpret_cast<float2*>(out);

  float2 x[kC];
#pragma unroll
  for (int c = 0; c < kC; ++c)
    x[c] = X2[(b*kC + c)*(kT/2) + tq];

  __syncthreads();

#pragma unroll 2
  for (int o = 0; o < kOUT; ++o) {
    const float4* w4 = reinterpret_cast<const float4*>(s_attn + o * kC);
    float a0x = 0.f, a0y = 0.f, a1x = 0.f, a1y = 0.f;
#pragma unroll
    for (int c4 = 0; c4 < 8; ++c4) {
      const float4 w = w4[c4];
      a0x = fmaf(w.x, x[4*c4+0].x, a0x); a0y = fmaf(w.x, x[4*c4+0].y, a0y);
      a0x = fmaf(w.y, x[4*c4+1].x, a0x); a0y = fmaf(w.y, x[4*c4+1].y, a0y);
      a0x = fmaf(w.z, x[4*c4+2].x, a0x); a0y = fmaf(w.z, x[4*c4+2].y, a0y);
      a0x = fmaf(w.w, x[4*c4+3].x, a0x); a0y = fmaf(w.w, x[4*c4+3].y, a0y);
    }
#pragma unroll
    for (int c4 = 8; c4 < 16; ++c4) {
      const float4 w = w4[c4];
      a1x = fmaf(w.x, x[4*c4+0].x, a1x); a1y = fmaf(w.x, x[4*c4+0].y, a1y);
      a1x = fmaf(w.y, x[4*c4+1].x, a1x); a1y = fmaf(w.y, x[4*c4+1].y, a1y);
      a1x = fmaf(w.z, x[4*c4+2].x, a1x); a1y = fmaf(w.z, x[4*c4+2].y, a1y);
      a1x = fmaf(w.w, x[4*c4+3].x, a1x); a1y = fmaf(w.w, x[4*c4+3].y, a1y);
    }
    float2 r;
    r.x = a0x + a1x;
    r.y = a0y + a1y;
    out2[(b*kOUT + o)*(kT/2) + tq] = r;
  }
}

// ---------------------------------------------------------------------------
extern "C" void kernel_launch(void* const* d_in, const int* in_sizes, int n_in,
                              void* d_out, int out_size, void* d_ws, size_t ws_size,
                              hipStream_t stream) {
  (void)in_sizes; (void)n_in; (void)out_size; (void)ws_size;
  const float* X         = (const float*)d_in[0];
  const float* positions = (const float*)d_in[1];
  const int*   drop_idx  = (const int*)d_in[2];
  const float* z_real    = (const float*)d_in[3];
  const float* z_imag    = (const float*)d_in[4];
  float* out = (float*)d_out;

  float* part = (float*)d_ws;                       // [kNFC][B][OUT][C] f32, 8.45 MB
  float* attn = part + (size_t)kNFC*kB*kOUT*kC;     // [B][OUT][C] f32, 1.06 MB

  sa_phase_dot<<<kB*kNFC, 512, 0, stream>>>(positions, z_real, z_imag, part);
  sa_softmax<<<kB*kOUT, 64, 0, stream>>>(part, positions, drop_idx, attn);
  sa_apply<<<kB*16, 256, 0, stream>>>(X, attn, out);
}

// Round 4
// 240.257 us; speedup vs baseline: 1.9023x; 1.4365x over previous
//
#include <hip/hip_runtime.h>
#include <math.h>

typedef __bf16 bf16x8 __attribute__((ext_vector_type(8)));
typedef unsigned short u16x8 __attribute__((ext_vector_type(8)));
typedef float f32x4 __attribute__((ext_vector_type(4)));

namespace {
constexpr int kB   = 32;
constexpr int kC   = 64;
constexpr int kT   = 8192;
constexpr int kOUT = 129;
constexpr int kKK  = 1024;   // K*K
constexpr int kNFC = 16;     // f-chunks
constexpr int kFCH = 64;     // f per chunk
}

__device__ inline float sin2pi(float r) {  // r in revolutions, [0,1)
  float o; asm("v_sin_f32 %0, %1" : "=v"(o) : "v"(r)); return o;
}
__device__ inline float cos2pi(float r) {
  float o; asm("v_cos_f32 %0, %1" : "=v"(o) : "v"(r)); return o;
}
__device__ inline unsigned short f2bf_rne(float f) {
  unsigned int u = __builtin_bit_cast(unsigned int, f);
  return (unsigned short)((u + 0x7fffu + ((u >> 16) & 1u)) >> 16);
}
__device__ inline float bf2f(unsigned short h) {
  return __builtin_bit_cast(float, (unsigned int)h << 16);
}

// ---------------------------------------------------------------------------
// Kernel 1: partial a[b,o,c] over one f-chunk of 64 frequencies, bf16 out.
// grid = B*16 = 512 blocks (2/CU), 512 threads. LDS: z chunk only (66 KB).
// Trig via HW v_sin/v_cos on fract(x*k + y*l) (revolutions), recomputed per
// lane and amortized over 17 o-accumulators. z read as wave-uniform b128
// broadcast. part written as bf16 (ws stays 9.50 MB).
// ---------------------------------------------------------------------------
__global__ __launch_bounds__(512) void sa_phase_dot(
    const float* __restrict__ positions,
    const float* __restrict__ z_real,
    const float* __restrict__ z_imag,
    unsigned short* __restrict__ part)
{
  __shared__ float4 s_zr[kOUT * 16];  // [o][q4] 129 x 16 float4 = 33 KB
  __shared__ float4 s_zi[kOUT * 16];

  const int b   = blockIdx.x >> 4;
  const int fc  = blockIdx.x & 15;
  const int tid = threadIdx.x;

  const float4* zr4 = reinterpret_cast<const float4*>(z_real);
  const float4* zi4 = reinterpret_cast<const float4*>(z_imag);
  for (int i = tid; i < kOUT * 16; i += 512) {
    const int o = i >> 4, q = i & 15;
    s_zr[i] = zr4[o * (kKK / 4) + fc * 16 + q];
    s_zi[i] = zi4[o * (kKK / 4) + fc * 16 + q];
  }

  const int og = tid >> 6;   // wave 0..7
  const int c  = tid & 63;   // channel = lane
  const float2 p = reinterpret_cast<const float2*>(positions)[b * kC + c];
  const float x = p.x, y = p.y;

  __syncthreads();

  float acc[17];
#pragma unroll
  for (int j = 0; j < 17; ++j) acc[j] = 0.f;

  const float lbase = (float)(fc * 2 + 1);
  for (int q4 = 0; q4 < 16; ++q4) {
    float cs[4], sn[4];
#pragma unroll
    for (int i = 0; i < 4; ++i) {
      const int ff = q4 * 4 + i;                   // 0..63 within chunk
      const float kf = (float)((ff & 31) + 1);     // coef_k
      const float lf = lbase + (float)(ff >> 5);   // coef_l
      // match reference rounding: fl(fl(x*k) + fl(y*l)); no fma contraction
      const float w = __fadd_rn(__fmul_rn(x, kf), __fmul_rn(y, lf));
      const float r = w - floorf(w);               // revolutions in [0,1)
      sn[i] = sin2pi(r);
      cs[i] = cos2pi(r);
    }
#pragma unroll
    for (int j = 0; j < 17; ++j) {
      const int o = og + 8 * j;
      if (o < kOUT) {
        const float4 zr = s_zr[o * 16 + q4];   // wave-uniform broadcast
        const float4 zi = s_zi[o * 16 + q4];
        float a = acc[j];
        a = fmaf(zr.x, cs[0], a); a = fmaf(zi.x, sn[0], a);
        a = fmaf(zr.y, cs[1], a); a = fmaf(zi.y, sn[1], a);
        a = fmaf(zr.z, cs[2], a); a = fmaf(zi.z, sn[2], a);
        a = fmaf(zr.w, cs[3], a); a = fmaf(zi.w, sn[3], a);
        acc[j] = a;
      }
    }
  }

#pragma unroll
  for (int j = 0; j < 17; ++j) {
    const int o = og + 8 * j;
    if (o < kOUT)
      part[(((size_t)fc * kB + b) * kOUT + o) * kC + c] = f2bf_rne(acc[j]);
  }
}

// ---------------------------------------------------------------------------
// Kernel 2: reduce bf16 partials, mask, softmax over c, emit split-bf16 attn.
// grid = B*OUT one-wave blocks.
// ---------------------------------------------------------------------------
__global__ __launch_bounds__(64) void sa_softmax(
    const unsigned short* __restrict__ part,
    const float* __restrict__ positions,
    const int*   __restrict__ drop_idx,
    unsigned short* __restrict__ a_hi,
    unsigned short* __restrict__ a_lo)
{
  const int bo = blockIdx.x;
  const int b  = bo / kOUT;
  const int o  = bo - b * kOUT;
  const int c  = threadIdx.x;

  float a = 0.f;
#pragma unroll
  for (int fc = 0; fc < kNFC; ++fc)
    a += bf2f(part[(((size_t)fc * kB + b) * kOUT + o) * kC + c]);

  const float2 p  = reinterpret_cast<const float2*>(positions)[b * kC + c];
  const int    di = drop_idx[b];
  const float2 pd = reinterpret_cast<const float2*>(positions)[b * kC + di];
  const float dx = p.x - pd.x;
  const float dy = p.y - pd.y;
  const float d2 = __fadd_rn(__fmul_rn(dx, dx), __fmul_rn(dy, dy));
  if (d2 < 0.1f) a = -1e9f;

  float m = a;
#pragma unroll
  for (int off = 32; off; off >>= 1) m = fmaxf(m, __shfl_xor(m, off));
  const float e = expf(a - m);
  float s = e;
#pragma unroll
  for (int off = 32; off; off >>= 1) s += __shfl_xor(s, off);

  const float att = e / s;
  const unsigned short h = f2bf_rne(att);
  const float res = att - bf2f(h);
  a_hi[((size_t)b * kOUT + o) * kC + c] = h;
  a_lo[((size_t)b * kOUT + o) * kC + c] = f2bf_rne(res);
}

// ---------------------------------------------------------------------------
// Kernel 3: out[b,o,t] = sum_c attn[b,o,c] * X[b,c,t] via bf16 MFMA, split
// precision: Ah*Xh + Ah*Xl + Al*Xh (err ~2^-18). grid = B*128 blocks
// (64-t chunk each), 256 threads = 4 waves; wave owns a 16-t sub-tile and
// loops 9 M-tiles of 16 o. A staged in LDS XOR-swizzled; X frags from global.
// mfma_f32_16x16x32_bf16 model: A lane l -> row l&15, k = 8*(l>>4)+j;
// B lane l -> col l&15, k = 8*(l>>4)+j; D lane l -> col l&15, row (l>>4)*4+r.
// ---------------------------------------------------------------------------
__global__ __launch_bounds__(256) void sa_apply_mfma(
    const float* __restrict__ X,
    const unsigned short* __restrict__ a_hi,
    const unsigned short* __restrict__ a_lo,
    float* __restrict__ out)
{
  __shared__ unsigned short s_a[2 * 144 * kC];  // hi tile + lo tile, 36 KB

  const int b   = blockIdx.x >> 7;
  const int tc  = blockIdx.x & 127;
  const int t0  = tc * 64;
  const int tid = threadIdx.x;

  // stage A (split) into LDS, swizzled: byte = row*128 + ((ch*16) ^ ((row&7)<<4))
  {
    char* sb = reinterpret_cast<char*>(s_a);
    for (int i = tid; i < 2 * 144 * 8; i += 256) {
      const int tile = (i >= 144 * 8) ? 1 : 0;
      const int r    = (i >> 3) - tile * 144;
      const int ch   = i & 7;
      float4 v;
      if (r < kOUT) {
        const unsigned short* src =
            (tile ? a_lo : a_hi) + ((size_t)b * kOUT + r) * kC + ch * 8;
        v = *reinterpret_cast<const float4*>(src);
      } else {
        v = make_float4(0.f, 0.f, 0.f, 0.f);   // pad rows 129..143
      }
      const int byte = tile * (144 * 128) + r * 128 + ((ch * 16) ^ ((r & 7) << 4));
      *reinterpret_cast<float4*>(sb + byte) = v;
    }
  }

  const int wave = tid >> 6;
  const int lane = tid & 63;
  const int t    = t0 + wave * 16 + (lane & 15);
  const int cg   = lane >> 4;   // k-group 0..3

  // X fragment loads (global, per-lane strided) + split into bf16 hi/lo
  const float* Xb = X + (size_t)b * kC * kT;
  float xv[16];
#pragma unroll
  for (int s2 = 0; s2 < 2; ++s2)
#pragma unroll
    for (int j = 0; j < 8; ++j)
      xv[s2 * 8 + j] = Xb[(size_t)(s2 * 32 + cg * 8 + j) * kT + t];

  u16x8 uh0, uh1, ul0, ul1;
#pragma unroll
  for (int j = 0; j < 8; ++j) {
    float f = xv[j];
    unsigned short h = f2bf_rne(f);
    uh0[j] = h; ul0[j] = f2bf_rne(f - bf2f(h));
    f = xv[8 + j];
    h = f2bf_rne(f);
    uh1[j] = h; ul1[j] = f2bf_rne(f - bf2f(h));
  }
  const bf16x8 Xh0 = __builtin_bit_cast(bf16x8, uh0);
  const bf16x8 Xh1 = __builtin_bit_cast(bf16x8, uh1);
  const bf16x8 Xl0 = __builtin_bit_cast(bf16x8, ul0);
  const bf16x8 Xl1 = __builtin_bit_cast(bf16x8, ul1);

  __syncthreads();

  const char* sb = reinterpret_cast<const char*>(s_a);
  float* outb = out + (size_t)b * kOUT * kT;

  for (int m = 0; m < 9; ++m) {
    const int row  = m * 16 + (lane & 15);
    const int base = row * 128;
    const int sw   = (row & 7) << 4;
    const int gb   = cg * 16;

    const bf16x8 Ah0 = *reinterpret_cast<const bf16x8*>(sb + base + ((gb     ) ^ sw));
    const bf16x8 Ah1 = *reinterpret_cast<const bf16x8*>(sb + base + ((gb + 64) ^ sw));
    const bf16x8 Al0 = *reinterpret_cast<const bf16x8*>(sb + 144 * 128 + base + ((gb     ) ^ sw));
    const bf16x8 Al1 = *reinterpret_cast<const bf16x8*>(sb + 144 * 128 + base + ((gb + 64) ^ sw));

    f32x4 acc = {0.f, 0.f, 0.f, 0.f};
    acc = __builtin_amdgcn_mfma_f32_16x16x32_bf16(Ah0, Xh0, acc, 0, 0, 0);
    acc = __builtin_amdgcn_mfma_f32_16x16x32_bf16(Ah1, Xh1, acc, 0, 0, 0);
    acc = __builtin_amdgcn_mfma_f32_16x16x32_bf16(Al0, Xh0, acc, 0, 0, 0);
    acc = __builtin_amdgcn_mfma_f32_16x16x32_bf16(Al1, Xh1, acc, 0, 0, 0);
    acc = __builtin_amdgcn_mfma_f32_16x16x32_bf16(Ah0, Xl0, acc, 0, 0, 0);
    acc = __builtin_amdgcn_mfma_f32_16x16x32_bf16(Ah1, Xl1, acc, 0, 0, 0);

#pragma unroll
    for (int r = 0; r < 4; ++r) {
      const int o = m * 16 + cg * 4 + r;
      if (o < kOUT) outb[(size_t)o * kT + t] = acc[r];
    }
  }
}

// ---------------------------------------------------------------------------
extern "C" void kernel_launch(void* const* d_in, const int* in_sizes, int n_in,
                              void* d_out, int out_size, void* d_ws, size_t ws_size,
                              hipStream_t stream) {
  (void)in_sizes; (void)n_in; (void)out_size; (void)ws_size;
  const float* X         = (const float*)d_in[0];
  const float* positions = (const float*)d_in[1];
  const int*   drop_idx  = (const int*)d_in[2];
  const float* z_real    = (const float*)d_in[3];
  const float* z_imag    = (const float*)d_in[4];
  float* out = (float*)d_out;

  unsigned short* part = (unsigned short*)d_ws;            // [16][32][129][64] bf16, 8.45 MB
  unsigned short* ahi  = part + (size_t)kNFC * kB * kOUT * kC;  // [32][129][64] bf16
  unsigned short* alo  = ahi + (size_t)kB * kOUT * kC;          // [32][129][64] bf16

  sa_phase_dot<<<kB * kNFC, 512, 0, stream>>>(positions, z_real, z_imag, part);
  sa_softmax<<<kB * kOUT, 64, 0, stream>>>(part, positions, drop_idx, ahi, alo);
  sa_apply_mfma<<<kB * 128, 256, 0, stream>>>(X, ahi, alo, out);
}